// Round 2
// baseline (412.419 us; speedup 1.0000x reference)
//
#include <hip/hip_runtime.h>
#include <hip/hip_fp16.h>
#include <math.h>

// SSIM loss, fully fused single kernel:
// 5 separable 11-tap Gaussian convs + SSIM map + global mean.
// 64x32 output tile / 256-thread block.
// Horizontal pass reads global directly (tile window is L1-resident),
// results packed to 3 LDS words/pixel (2x half2 + 1x fp32) -> 32.8 KB LDS
// -> 4 blocks/CU (50% occupancy cap vs previous 25%).
// Block partial sums land in d_ws[0] via atomicAdd; the last block to
// increment the counter writes the final scalar (no second kernel).

#define KW 11
#define RAD 5
#define TILE_W 64
#define TILE_H 32
#define IN_H (TILE_H + 2 * RAD)   // 42
#define HS 65                     // word stride for h arrays (2-way max)
#define IMG_H 512
#define IMG_W 512
#define NPLANES 48                // 16*3
#define NBLOCKS (8 * 16 * NPLANES)  // 6144
#define NPIXF (16.0f * 3.0f * 512.0f * 512.0f)

struct GaussW { float g[KW]; };

__global__ __launch_bounds__(256, 4) void ssim_fused(
    const float* __restrict__ img1, const float* __restrict__ img2,
    float* __restrict__ accum, unsigned* __restrict__ count,
    float* __restrict__ out, GaussW W)
{
    __shared__ __half2 hxy[IN_H][HS];    // (gauss-h of x, gauss-h of y)
    __shared__ __half2 hxxyy[IN_H][HS];  // (gauss-h of x*x, of y*y)
    __shared__ float   hxys[IN_H][HS];   // gauss-h of x*y (fp32)
    __shared__ float   red[4];

    const int tid = threadIdx.x;
    const int plane = blockIdx.y;
    const int tile = blockIdx.x;
    const int tx = tile & 7;
    const int ty = tile >> 3;
    const int c0 = tx * TILE_W;
    const int r0 = ty * TILE_H;
    const float* __restrict__ p1 = img1 + (size_t)plane * (IMG_H * IMG_W);
    const float* __restrict__ p2 = img2 + (size_t)plane * (IMG_H * IMG_W);

    // cols touched: [c0-5, c0+68]; safe iff fully in [0,512)
    const bool colsafe = (c0 >= RAD) && (c0 + 68 < IMG_W);

    // ---- horizontal pass: global -> registers -> packed LDS ----
    // thread -> (row = tid>>3 [+32], col group of 8 = (tid&7)*8)
    const int cg = (tid & 7) * 8;
    const int row0 = tid >> 3;
    #pragma unroll
    for (int rr = 0; rr < 2; ++rr) {
        const int row = row0 + rr * 32;
        if (row < IN_H) {
            const int gr = r0 - RAD + row;
            const bool rowok = (unsigned)gr < (unsigned)IMG_H;
            const int gc0 = c0 - RAD + cg;
            const float* a = p1 + (ptrdiff_t)gr * IMG_W + gc0;
            const float* b = p2 + (ptrdiff_t)gr * IMG_W + gc0;

            float ax[8] = {}, ay[8] = {}, axx[8] = {}, ayy[8] = {}, axy[8] = {};

            auto taps = [&](int j, float xv, float yv) {
                const float xx = xv * xv, yy = yv * yv, xy = xv * yv;
                #pragma unroll
                for (int o = 0; o < 8; ++o) {
                    const int t = j - o;
                    if (t >= 0 && t < KW) {
                        const float w = W.g[t];
                        ax[o]  += w * xv;
                        ay[o]  += w * yv;
                        axx[o] += w * xx;
                        ayy[o] += w * yy;
                        axy[o] += w * xy;
                    }
                }
            };

            if (rowok && colsafe) {
                #pragma unroll
                for (int j = 0; j < 18; ++j)
                    taps(j, a[j], b[j]);
            } else if (rowok) {
                #pragma unroll
                for (int j = 0; j < 18; ++j) {
                    float xv = 0.f, yv = 0.f;
                    if ((unsigned)(gc0 + j) < (unsigned)IMG_W) {
                        xv = a[j];
                        yv = b[j];
                    }
                    taps(j, xv, yv);
                }
            }
            // (!rowok -> accumulators stay zero; still write the zeros)

            #pragma unroll
            for (int o = 0; o < 8; ++o) {
                const int col = cg + o;
                hxy[row][col]   = __floats2half2_rn(ax[o], ay[o]);
                hxxyy[row][col] = __floats2half2_rn(axx[o], ayy[o]);
                hxys[row][col]  = axy[o];
            }
        }
    }
    __syncthreads();

    // ---- vertical pass + SSIM map ----
    // thread -> (col = tid&63, 8 output rows starting at (tid>>6)*8)
    const int col = tid & 63;
    const int rbase = (tid >> 6) * 8;
    float ox[8] = {}, oy[8] = {}, oxx[8] = {}, oyy[8] = {}, oxy[8] = {};
    #pragma unroll
    for (int m = 0; m < 18; ++m) {
        const int hr = rbase + m;
        const float2 f01 = __half22float2(hxy[hr][col]);
        const float2 f23 = __half22float2(hxxyy[hr][col]);
        const float v4 = hxys[hr][col];
        #pragma unroll
        for (int o = 0; o < 8; ++o) {
            const int t = m - o;
            if (t >= 0 && t < KW) {
                const float w = W.g[t];
                ox[o]  += w * f01.x;
                oy[o]  += w * f01.y;
                oxx[o] += w * f23.x;
                oyy[o] += w * f23.y;
                oxy[o] += w * v4;
            }
        }
    }

    const float C1 = 1.0e-4f;  // (0.01*L)^2
    const float C2 = 9.0e-4f;  // (0.03*L)^2
    float ssum = 0.f;
    #pragma unroll
    for (int o = 0; o < 8; ++o) {
        const float mu1 = ox[o], mu2 = oy[o];
        const float mu1sq = mu1 * mu1;
        const float mu2sq = mu2 * mu2;
        const float mu12  = mu1 * mu2;
        const float sg1  = oxx[o] - mu1sq;
        const float sg2  = oyy[o] - mu2sq;
        const float sg12 = oxy[o] - mu12;
        const float num = (2.f * mu12 + C1) * (2.f * sg12 + C2);
        const float den = (mu1sq + mu2sq + C1) * (sg1 + sg2 + C2);
        ssum += num / den;
    }

    // ---- block reduction -> device atomic -> last block finishes ----
    #pragma unroll
    for (int off = 32; off > 0; off >>= 1)
        ssum += __shfl_down(ssum, off, 64);
    if ((tid & 63) == 0) red[tid >> 6] = ssum;
    __syncthreads();
    if (tid == 0) {
        const float bsum = red[0] + red[1] + red[2] + red[3];
        atomicAdd(accum, bsum);
        __threadfence();
        const unsigned prev = atomicAdd(count, 1u);
        if (prev == (unsigned)(NBLOCKS - 1)) {
            __threadfence();
            const float tot = atomicAdd(accum, 0.0f);  // coherent read
            out[0] = 1.0f - tot / NPIXF;
        }
    }
}

extern "C" void kernel_launch(void* const* d_in, const int* in_sizes, int n_in,
                              void* d_out, int out_size, void* d_ws, size_t ws_size,
                              hipStream_t stream) {
    const float* img1 = (const float*)d_in[0];
    const float* img2 = (const float*)d_in[1];
    float* out = (float*)d_out;
    float* accum = (float*)d_ws;
    unsigned* count = (unsigned*)d_ws + 2;

    hipMemsetAsync(d_ws, 0, 16, stream);  // zero accumulator + counter

    // Gaussian weights on host (double exp, normalized) — matches the
    // reference's float32 window to ~1e-8.
    GaussW W;
    double gd[KW], sum = 0.0;
    for (int i = 0; i < KW; ++i) {
        const double d = (double)(i - KW / 2);
        gd[i] = exp(-(d * d) / (2.0 * 1.5 * 1.5));
        sum += gd[i];
    }
    for (int i = 0; i < KW; ++i) W.g[i] = (float)(gd[i] / sum);

    dim3 grid(8 * 16, NPLANES);
    ssim_fused<<<grid, 256, 0, stream>>>(img1, img2, accum, count, out, W);
}

// Round 5
// 363.338 us; speedup vs baseline: 1.1351x; 1.1351x over previous
//
#include <hip/hip_runtime.h>
#include <hip/hip_fp16.h>
#include <math.h>

// SSIM loss, fully fused single kernel:
// 5 separable 11-tap Gaussian convs + SSIM map + global mean.
// 64x32 output tile / 256-thread block.
// Horizontal pass reads global directly (tile window is L1/L2-resident),
// results packed to 3 LDS words/pixel (2x half2 + 1x fp32) = 32768 B LDS
// -> 4-5 blocks/CU. launch_bounds(256,2): VGPR cap 128 (NOT (256,4): that
// caps VGPRs at 64 and spills ~60 MB of scratch to HBM — round-2 lesson).
// Block partials -> atomicAdd; last block writes the final scalar.

#define KW 11
#define RAD 5
#define TILE_W 64
#define TILE_H 32
#define IN_H (TILE_H + 2 * RAD)   // 42
#define HS 65                     // word stride (breaks 8-row write conflict)
#define IMG_H 512
#define IMG_W 512
#define NPLANES 48                // 16*3
#define NBLOCKS (8 * 16 * NPLANES)  // 6144
#define NPIXF (16.0f * 3.0f * 512.0f * 512.0f)

struct GaussW { float g[KW]; };

__global__ __launch_bounds__(256, 2) void ssim_fused(
    const float* __restrict__ img1, const float* __restrict__ img2,
    float* __restrict__ accum, unsigned* __restrict__ count,
    float* __restrict__ out, GaussW W)
{
    __shared__ __half2 hxy[IN_H][HS];    // (gauss-h of x, gauss-h of y)
    __shared__ __half2 hxxyy[IN_H][HS];  // (gauss-h of x*x, of y*y)
    __shared__ float   hxys[IN_H][HS];   // gauss-h of x*y (fp32)
    // total: 3 * 42 * 65 * 4 = 32760 B -> 32768 alloc; no extra red[] array

    const int tid = threadIdx.x;
    const int plane = blockIdx.y;
    const int tile = blockIdx.x;
    const int tx = tile & 7;
    const int ty = tile >> 3;
    const int c0 = tx * TILE_W;
    const int r0 = ty * TILE_H;
    const float* __restrict__ p1 = img1 + (size_t)plane * (IMG_H * IMG_W);
    const float* __restrict__ p2 = img2 + (size_t)plane * (IMG_H * IMG_W);

    // cols touched: [c0-5, c0+68]; safe iff fully in [0,512)
    const bool colsafe = (c0 >= RAD) && (c0 + 68 < IMG_W);

    // ---- horizontal pass: global -> registers -> packed LDS ----
    // thread -> (row = tid>>3 [+32], col group of 8 = (tid&7)*8)
    const int cg = (tid & 7) * 8;
    const int row0 = tid >> 3;
    #pragma unroll
    for (int rr = 0; rr < 2; ++rr) {
        const int row = row0 + rr * 32;
        if (row < IN_H) {
            const int gr = r0 - RAD + row;
            const bool rowok = (unsigned)gr < (unsigned)IMG_H;
            const int gc0 = c0 - RAD + cg;
            const float* a = p1 + (ptrdiff_t)gr * IMG_W + gc0;
            const float* b = p2 + (ptrdiff_t)gr * IMG_W + gc0;

            float ax[8] = {}, ay[8] = {}, axx[8] = {}, ayy[8] = {}, axy[8] = {};

            auto taps = [&](int j, float xv, float yv) {
                const float xx = xv * xv, yy = yv * yv, xy = xv * yv;
                #pragma unroll
                for (int o = 0; o < 8; ++o) {
                    const int t = j - o;
                    if (t >= 0 && t < KW) {
                        const float w = W.g[t];
                        ax[o]  += w * xv;
                        ay[o]  += w * yv;
                        axx[o] += w * xx;
                        ayy[o] += w * yy;
                        axy[o] += w * xy;
                    }
                }
            };

            if (rowok && colsafe) {
                #pragma unroll
                for (int j = 0; j < 18; ++j)
                    taps(j, a[j], b[j]);
            } else if (rowok) {
                #pragma unroll
                for (int j = 0; j < 18; ++j) {
                    float xv = 0.f, yv = 0.f;
                    if ((unsigned)(gc0 + j) < (unsigned)IMG_W) {
                        xv = a[j];
                        yv = b[j];
                    }
                    taps(j, xv, yv);
                }
            }
            // (!rowok -> accumulators stay zero; still write the zeros)

            #pragma unroll
            for (int o = 0; o < 8; ++o) {
                const int col = cg + o;
                hxy[row][col]   = __floats2half2_rn(ax[o], ay[o]);
                hxxyy[row][col] = __floats2half2_rn(axx[o], ayy[o]);
                hxys[row][col]  = axy[o];
            }
        }
    }
    __syncthreads();

    // ---- vertical pass + SSIM map ----
    // thread -> (col = tid&63, 8 output rows starting at (tid>>6)*8)
    const int col = tid & 63;
    const int rbase = (tid >> 6) * 8;
    float ox[8] = {}, oy[8] = {}, oxx[8] = {}, oyy[8] = {}, oxy[8] = {};
    #pragma unroll
    for (int m = 0; m < 18; ++m) {
        const int hr = rbase + m;
        const float2 f01 = __half22float2(hxy[hr][col]);
        const float2 f23 = __half22float2(hxxyy[hr][col]);
        const float v4 = hxys[hr][col];
        #pragma unroll
        for (int o = 0; o < 8; ++o) {
            const int t = m - o;
            if (t >= 0 && t < KW) {
                const float w = W.g[t];
                ox[o]  += w * f01.x;
                oy[o]  += w * f01.y;
                oxx[o] += w * f23.x;
                oyy[o] += w * f23.y;
                oxy[o] += w * v4;
            }
        }
    }

    const float C1 = 1.0e-4f;  // (0.01*L)^2
    const float C2 = 9.0e-4f;  // (0.03*L)^2
    float ssum = 0.f;
    #pragma unroll
    for (int o = 0; o < 8; ++o) {
        const float mu1 = ox[o], mu2 = oy[o];
        const float mu1sq = mu1 * mu1;
        const float mu2sq = mu2 * mu2;
        const float mu12  = mu1 * mu2;
        const float sg1  = oxx[o] - mu1sq;
        const float sg2  = oyy[o] - mu2sq;
        const float sg12 = oxy[o] - mu12;
        const float num = (2.f * mu12 + C1) * (2.f * sg12 + C2);
        const float den = (mu1sq + mu2sq + C1) * (sg1 + sg2 + C2);
        ssum += num / den;
    }

    // ---- reductions: wave shuffle -> LDS (reuse hxys row 0) -> atomic ----
    #pragma unroll
    for (int off = 32; off > 0; off >>= 1)
        ssum += __shfl_down(ssum, off, 64);
    __syncthreads();                      // all h-array reads done; safe to reuse
    if ((tid & 63) == 0) hxys[0][tid >> 6] = ssum;
    __syncthreads();
    if (tid == 0) {
        const float bsum = hxys[0][0] + hxys[0][1] + hxys[0][2] + hxys[0][3];
        atomicAdd(accum, bsum);
        __threadfence();
        const unsigned prev = atomicAdd(count, 1u);
        if (prev == (unsigned)(NBLOCKS - 1)) {
            __threadfence();
            const float tot = atomicAdd(accum, 0.0f);  // coherent read
            out[0] = 1.0f - tot / NPIXF;
        }
    }
}

extern "C" void kernel_launch(void* const* d_in, const int* in_sizes, int n_in,
                              void* d_out, int out_size, void* d_ws, size_t ws_size,
                              hipStream_t stream) {
    const float* img1 = (const float*)d_in[0];
    const float* img2 = (const float*)d_in[1];
    float* out = (float*)d_out;
    float* accum = (float*)d_ws;
    unsigned* count = (unsigned*)d_ws + 2;

    hipMemsetAsync(d_ws, 0, 16, stream);  // zero accumulator + counter

    // Gaussian weights on host (double exp, normalized) — matches the
    // reference's float32 window to ~1e-8.
    GaussW W;
    double gd[KW], sum = 0.0;
    for (int i = 0; i < KW; ++i) {
        const double d = (double)(i - KW / 2);
        gd[i] = exp(-(d * d) / (2.0 * 1.5 * 1.5));
        sum += gd[i];
    }
    for (int i = 0; i < KW; ++i) W.g[i] = (float)(gd[i] / sum);

    dim3 grid(8 * 16, NPLANES);
    ssim_fused<<<grid, 256, 0, stream>>>(img1, img2, accum, count, out, W);
}

// Round 6
// 307.140 us; speedup vs baseline: 1.3428x; 1.1830x over previous
//
#include <hip/hip_runtime.h>
#include <hip/hip_fp16.h>
#include <math.h>

// SSIM loss, fully fused single kernel.
// R5 lesson: direct-global h-pass thrashes L1 (4 blocks x 25KB > 32KB L1),
// inner-loop loads run at L2/HBM latency, VALUBusy 20%, 285us.
// R6: all inner loops LDS-only again (R1 property) + packed layouts (R5
// property): s = half2(x,y) 1 word/pixel; h = {half2(hx,hy),half2(hxx,hyy)}
// pairs (b128 writes / b64 reads) + fp32 hxy plane. 46.4KB LDS -> 3 blk/CU.
// Bounds handled once at staging -> branch-free h-pass.

#define KW 11
#define RAD 5
#define TILE_W 64
#define TILE_H 32
#define IN_W 74                   // TILE_W + 10
#define IN_H 42                   // TILE_H + 10
#define SW 76                     // s stride (words); (12r+8g+j) bank-uniform
#define HP 66                     // hp stride (pixels); 528B/row: 16B-aligned, b128 starts tile banks
#define H5 68                     // hx5 stride (words); 272B/row: 16B-aligned
#define IMG_H 512
#define IMG_W 512
#define NPLANES 48                // 16*3
#define NBLOCKS (8 * 16 * NPLANES)  // 6144
#define NPIXF (16.0f * 3.0f * 512.0f * 512.0f)

struct GaussW { float g[KW]; };

__device__ __forceinline__ unsigned pkh2(float a, float b) {
    __half2 h = __floats2half2_rn(a, b);
    union { __half2 h; unsigned u; } c; c.h = h; return c.u;
}
__device__ __forceinline__ float2 uph2(unsigned u) {
    union { unsigned u; __half2 h; } c; c.u = u;
    return __half22float2(c.h);
}

__global__ __launch_bounds__(256, 2) void ssim_fused(
    const float* __restrict__ img1, const float* __restrict__ img2,
    float* __restrict__ accum, unsigned* __restrict__ count,
    float* __restrict__ out, GaussW W)
{
    __shared__ alignas(16) unsigned s[IN_H][SW];      // half2(x,y)
    __shared__ alignas(16) unsigned hp[IN_H][HP][2];  // {h2(hx,hy), h2(hxx,hyy)}
    __shared__ alignas(16) float    hx5[IN_H][H5];    // gauss-h of x*y, fp32
    // 12768 + 22176 + 11424 = 46368 B -> 3 blocks/CU

    const int tid = threadIdx.x;
    const int plane = blockIdx.y;
    const int tile = blockIdx.x;
    const int c0 = (tile & 7) * TILE_W;
    const int r0 = (tile >> 3) * TILE_H;
    const float* __restrict__ p1 = img1 + (size_t)plane * (IMG_H * IMG_W);
    const float* __restrict__ p2 = img2 + (size_t)plane * (IMG_H * IMG_W);

    // ---- stage: global -> half2(x,y) in LDS, zero-padded OOB ----
    for (int idx = tid; idx < IN_H * IN_W; idx += 256) {
        const int row = idx / IN_W;
        const int col = idx - row * IN_W;
        const int gr = r0 - RAD + row;
        const int gc = c0 - RAD + col;
        float x = 0.f, y = 0.f;
        if ((unsigned)gr < (unsigned)IMG_H && (unsigned)gc < (unsigned)IMG_W) {
            const ptrdiff_t o = (ptrdiff_t)gr * IMG_W + gc;
            x = p1[o];
            y = p2[o];
        }
        s[row][col] = pkh2(x, y);
    }
    __syncthreads();

    // ---- horizontal pass: LDS -> regs -> packed LDS (branch-free) ----
    // thread -> (row = tid>>3 [+32], col group of 8 = (tid&7)*8)
    const int cg = (tid & 7) * 8;
    const int row0 = tid >> 3;
    #pragma unroll
    for (int rr = 0; rr < 2; ++rr) {
        const int row = row0 + rr * 32;
        if (row < IN_H) {
            float ax[8] = {}, ay[8] = {}, axx[8] = {}, ayy[8] = {}, axy[8] = {};
            #pragma unroll
            for (int j = 0; j < 18; ++j) {
                const float2 xy = uph2(s[row][cg + j]);
                const float x = xy.x, y = xy.y;
                const float xx = x * x, yy = y * y, xyv = x * y;
                #pragma unroll
                for (int o = 0; o < 8; ++o) {
                    const int t = j - o;
                    if (t >= 0 && t < KW) {
                        const float w = W.g[t];
                        ax[o]  += w * x;
                        ay[o]  += w * y;
                        axx[o] += w * xx;
                        ayy[o] += w * yy;
                        axy[o] += w * xyv;
                    }
                }
            }
            // pack 8 pixels: 4x uint4 (b128) pairs + 2x float4 (b128) hxy
            uint4* dp = (uint4*)&hp[row][cg][0];
            #pragma unroll
            for (int k = 0; k < 4; ++k) {
                uint4 q;
                q.x = pkh2(ax[2 * k],     ay[2 * k]);
                q.y = pkh2(axx[2 * k],    ayy[2 * k]);
                q.z = pkh2(ax[2 * k + 1], ay[2 * k + 1]);
                q.w = pkh2(axx[2 * k + 1], ayy[2 * k + 1]);
                dp[k] = q;
            }
            float4* d5 = (float4*)&hx5[row][cg];
            d5[0] = make_float4(axy[0], axy[1], axy[2], axy[3]);
            d5[1] = make_float4(axy[4], axy[5], axy[6], axy[7]);
        }
    }
    __syncthreads();

    // ---- vertical pass + SSIM map ----
    // thread -> (col = tid&63, 8 output rows starting at (tid>>6)*8)
    const int col = tid & 63;
    const int rbase = (tid >> 6) * 8;
    float ox[8] = {}, oy[8] = {}, oxx[8] = {}, oyy[8] = {}, oxy[8] = {};
    #pragma unroll
    for (int m = 0; m < 18; ++m) {
        const int hr = rbase + m;
        const uint2 pw = *(const uint2*)&hp[hr][col][0];  // b64
        const float2 f01 = uph2(pw.x);   // (hx, hy)
        const float2 f23 = uph2(pw.y);   // (hxx, hyy)
        const float v4 = hx5[hr][col];
        #pragma unroll
        for (int o = 0; o < 8; ++o) {
            const int t = m - o;
            if (t >= 0 && t < KW) {
                const float w = W.g[t];
                ox[o]  += w * f01.x;
                oy[o]  += w * f01.y;
                oxx[o] += w * f23.x;
                oyy[o] += w * f23.y;
                oxy[o] += w * v4;
            }
        }
    }

    const float C1 = 1.0e-4f;  // (0.01*L)^2
    const float C2 = 9.0e-4f;  // (0.03*L)^2
    float ssum = 0.f;
    #pragma unroll
    for (int o = 0; o < 8; ++o) {
        const float mu1 = ox[o], mu2 = oy[o];
        const float mu1sq = mu1 * mu1;
        const float mu2sq = mu2 * mu2;
        const float mu12  = mu1 * mu2;
        const float sg1  = oxx[o] - mu1sq;
        const float sg2  = oyy[o] - mu2sq;
        const float sg12 = oxy[o] - mu12;
        const float num = (2.f * mu12 + C1) * (2.f * sg12 + C2);
        const float den = (mu1sq + mu2sq + C1) * (sg1 + sg2 + C2);
        ssum += num / den;
    }

    // ---- reductions: wave shuffle -> LDS (reuse hx5 row 0) -> atomic ----
    #pragma unroll
    for (int off = 32; off > 0; off >>= 1)
        ssum += __shfl_down(ssum, off, 64);
    __syncthreads();                      // all h reads done; safe to reuse
    if ((tid & 63) == 0) hx5[0][tid >> 6] = ssum;
    __syncthreads();
    if (tid == 0) {
        const float bsum = hx5[0][0] + hx5[0][1] + hx5[0][2] + hx5[0][3];
        atomicAdd(accum, bsum);
        __threadfence();
        const unsigned prev = atomicAdd(count, 1u);
        if (prev == (unsigned)(NBLOCKS - 1)) {
            __threadfence();
            const float tot = atomicAdd(accum, 0.0f);  // coherent read
            out[0] = 1.0f - tot / NPIXF;
        }
    }
}

extern "C" void kernel_launch(void* const* d_in, const int* in_sizes, int n_in,
                              void* d_out, int out_size, void* d_ws, size_t ws_size,
                              hipStream_t stream) {
    const float* img1 = (const float*)d_in[0];
    const float* img2 = (const float*)d_in[1];
    float* out = (float*)d_out;
    float* accum = (float*)d_ws;
    unsigned* count = (unsigned*)d_ws + 2;

    hipMemsetAsync(d_ws, 0, 16, stream);  // zero accumulator + counter

    // Gaussian weights on host (double exp, normalized) — matches the
    // reference's float32 window to ~1e-8.
    GaussW W;
    double gd[KW], sum = 0.0;
    for (int i = 0; i < KW; ++i) {
        const double d = (double)(i - KW / 2);
        gd[i] = exp(-(d * d) / (2.0 * 1.5 * 1.5));
        sum += gd[i];
    }
    for (int i = 0; i < KW; ++i) W.g[i] = (float)(gd[i] / sum);

    dim3 grid(8 * 16, NPLANES);
    ssim_fused<<<grid, 256, 0, stream>>>(img1, img2, accum, count, out, W);
}